// Round 1
// baseline (332.209 us; speedup 1.0000x reference)
//
#include <hip/hip_runtime.h>
#include <hip/hip_fp16.h>

// Problem constants
#define BB 8
#define NN 1024
#define FF 128
#define HH 8

typedef _Float16 f16;
typedef f16  f16x8 __attribute__((ext_vector_type(8)));
typedef float f32x4 __attribute__((ext_vector_type(4)));

__device__ __forceinline__ float lrelu(float x){ return fmaxf(x, 0.2f*x); }

// ---------------- preprocessing kernels ----------------

__global__ void k_conv_x(const float* __restrict__ x, f16* __restrict__ o){
  int i = (blockIdx.x*256 + threadIdx.x)*8;
  float4 a = *(const float4*)(x+i), b = *(const float4*)(x+i+4);
  f16x8 v;
  v[0]=(f16)a.x; v[1]=(f16)a.y; v[2]=(f16)a.z; v[3]=(f16)a.w;
  v[4]=(f16)b.x; v[5]=(f16)b.y; v[6]=(f16)b.z; v[7]=(f16)b.w;
  *(f16x8*)(o+i) = v;
}

// wB layout: [l][h][fc=f/8][c][8]  (B-fragment friendly: 8 consecutive f for fixed c)
__global__ void k_conv_w(const float* __restrict__ w1, const float* __restrict__ w2,
                         const float* __restrict__ w3, f16* __restrict__ wB){
  int e = blockIdx.x*256 + threadIdx.x;        // 49152 total
  int fc = e & 15, c = (e>>4)&127, h = (e>>11)&7, l = e>>14;
  const float* w = (l==0) ? w1 : ((l==1) ? w2 : w3);
  f16x8 v;
  #pragma unroll
  for(int j=0;j<8;j++) v[j] = (f16)w[(h*128 + fc*8 + j)*128 + c];
  *(f16x8*)(wB + (((l*8+h)*16 + fc)*128 + c)*8) = v;
}

// adjacency bitmask: am[b*1024+n][32 words]
__global__ void k_adjm(const float* __restrict__ adj, unsigned* __restrict__ am){
  int wv = threadIdx.x >> 6, lane = threadIdx.x & 63;
  int r = blockIdx.x*4 + wv;                  // 0..8191
  const float* row = adj + (long)r*1024;
  for(int g=0; g<16; g++){
    float v = row[g*64 + lane];
    unsigned long long mb = __ballot(v > 0.0f);
    if (lane == 0){
      am[r*32 + 2*g]   = (unsigned)mb;
      am[r*32 + 2*g+1] = (unsigned)(mb >> 32);
    }
  }
}

// ---------------- hp GEMM: hp = x @ w  (+tanh -> s,d) ----------------
// grid: b*64 + h*8 + it   (512 blocks, 256 threads)
// hpB layout: [b][h][jc=node/8][c][8]
__global__ __launch_bounds__(256,2) void k_hp(
    const f16* __restrict__ xin,      // [B][N][128] f16
    const f16* __restrict__ wBl,      // [H][16][128][8]
    const float* __restrict__ asrc, const float* __restrict__ adst,  // [H][128]
    f16* __restrict__ hpB,            // [B][H][128][128][8]
    float* __restrict__ sarr, float* __restrict__ darr)              // [B][H][1024]
{
  __shared__ f16 xs[128*136];     // x tile, later reused as tanh tile
  __shared__ float asl[128], adl[128];
  int t = threadIdx.x;
  int bid = blockIdx.x;
  int it = bid & 7, h = (bid>>3)&7, b = bid>>6;
  int i0 = it*128;
  // stage x tile [128][128] -> LDS padded stride 136
  {
    const f16* src = xin + (long)(b*1024 + i0)*128;
    int fc = t & 15, r0 = t >> 4;
    #pragma unroll
    for(int p=0;p<8;p++){
      int r = r0 + p*16;
      f16x8 v = *(const f16x8*)(src + r*128 + fc*8);
      *(f16x8*)(xs + r*136 + fc*8) = v;
    }
  }
  if (t < 128){ asl[t] = asrc[h*128+t]; adl[t] = adst[h*128+t]; }
  __syncthreads();

  int lane = t & 63, wv = t>>6, wr = wv>>1, wc = wv&1;
  int mq = lane & 15, quad = lane >> 4;
  f32x4 acc[4][4];
  #pragma unroll
  for(int a=0;a<4;a++)
    #pragma unroll
    for(int c=0;c<4;c++) acc[a][c] = (f32x4){0.f,0.f,0.f,0.f};

  const f16* wh = wBl + h*16*128*8;
  #pragma unroll
  for(int ks=0; ks<4; ks++){
    f16x8 af[4], bf[4];
    #pragma unroll
    for(int mt=0; mt<4; mt++)
      af[mt] = *(const f16x8*)(xs + (wr*64 + mt*16 + mq)*136 + ks*32 + quad*8);
    #pragma unroll
    for(int nt=0; nt<4; nt++){
      int c  = wc*64 + nt*16 + mq;
      int fc = ks*4 + quad;
      bf[nt] = *(const f16x8*)(wh + (fc*128 + c)*8);
    }
    #pragma unroll
    for(int mt=0; mt<4; mt++)
      #pragma unroll
      for(int nt=0; nt<4; nt++)
        acc[mt][nt] = __builtin_amdgcn_mfma_f32_16x16x32_f16(af[mt], bf[nt], acc[mt][nt], 0,0,0);
  }
  __syncthreads();          // xs dead -> reuse as tanh tile
  f16* tt = xs;             // [128][136]
  f16* hpb = hpB + (long)(b*8+h)*128*128*8;
  #pragma unroll
  for(int mt=0; mt<4; mt++){
    #pragma unroll
    for(int nt=0; nt<4; nt++){
      int c = wc*64 + nt*16 + mq;
      #pragma unroll
      for(int rg=0; rg<4; rg++){
        float v = acc[mt][nt][rg];
        int il = wr*64 + mt*16 + quad*4 + rg;    // 0..127
        int inode = i0 + il;
        hpb[((inode>>3)*128 + c)*8 + (inode&7)] = (f16)v;
        // tanh(v) = 1 - 2/(e^{2v}+1)
        float e2 = __expf(2.0f*v);
        float th = 1.0f - 2.0f*__builtin_amdgcn_rcpf(e2 + 1.0f);
        tt[il*136 + c] = (f16)th;
      }
    }
  }
  __syncthreads();
  // s,d reduction: 2 threads per row
  {
    int r = t>>1, hf = t&1;
    float s_p = 0.f, d_p = 0.f;
    #pragma unroll
    for(int q=0;q<8;q++){
      f16x8 tv = *(const f16x8*)(tt + r*136 + hf*64 + q*8);
      #pragma unroll
      for(int j=0;j<8;j++){
        float tvf = (float)tv[j];
        int c = hf*64 + q*8 + j;
        s_p = fmaf(tvf, asl[c], s_p);
        d_p = fmaf(tvf, adl[c], d_p);
      }
    }
    s_p += __shfl_xor(s_p, 1);
    d_p += __shfl_xor(d_p, 1);
    if (hf == 0){
      sarr[(b*8+h)*1024 + i0 + r] = s_p;
      darr[(b*8+h)*1024 + i0 + r] = d_p;
    }
  }
}

// ---------------- attention: out_h = softmax(mask(lrelu(s_i+d_j))) @ hp ----------------
// grid: b*64 + h*8 + it   (512 blocks, 256 threads)
__global__ __launch_bounds__(256,2) void k_attn(
    const f16* __restrict__ hpB,      // [B][H][128][128][8]
    const float* __restrict__ sarr, const float* __restrict__ darr,
    const unsigned* __restrict__ am,  // [B*1024][32]
    float* __restrict__ part)         // [B][H][1024][128] (zinv- and 1/8-scaled)
{
  __shared__ unsigned ams[128*33];
  __shared__ float dd[1024];
  __shared__ float ssr[128];
  __shared__ float mlr[128];
  __shared__ float zin[128];
  __shared__ float wred[4];
  __shared__ f16 Pl[128*40];
  int t = threadIdx.x;
  int bid = blockIdx.x;
  int it = bid & 7, h = (bid>>3)&7, b = bid>>6;
  int i0 = it*128;
  int bh = b*8 + h;
  // load d row, wave-reduce for global max
  {
    float4 v = *(const float4*)(darr + bh*1024 + t*4);
    ((float4*)dd)[t] = v;
    float mx = fmaxf(fmaxf(v.x,v.y), fmaxf(v.z,v.w));
    #pragma unroll
    for(int o=1;o<64;o<<=1) mx = fmaxf(mx, __shfl_xor(mx, o));
    if ((t&63)==0) wred[t>>6] = mx;
  }
  if (t < 128) ssr[t] = sarr[bh*1024 + i0 + t];
  // adjacency rows -> LDS (stride 33 to kill bank conflicts)
  {
    int r = t>>1, w0 = (t&1)*16;
    const unsigned* src = am + ((long)b*1024 + i0 + r)*32 + w0;
    uint4 a0 = *(const uint4*)(src),   a1 = *(const uint4*)(src+4);
    uint4 a2 = *(const uint4*)(src+8), a3 = *(const uint4*)(src+12);
    unsigned* dst = ams + r*33 + w0;
    dst[0]=a0.x; dst[1]=a0.y; dst[2]=a0.z; dst[3]=a0.w;
    dst[4]=a1.x; dst[5]=a1.y; dst[6]=a1.z; dst[7]=a1.w;
    dst[8]=a2.x; dst[9]=a2.y; dst[10]=a2.z; dst[11]=a2.w;
    dst[12]=a3.x; dst[13]=a3.y; dst[14]=a3.z; dst[15]=a3.w;
  }
  __syncthreads();
  {
    float Dm = fmaxf(fmaxf(wred[0],wred[1]), fmaxf(wred[2],wred[3]));
    if (t < 128) mlr[t] = lrelu(ssr[t] + Dm);   // exact upper bound of masked scores
  }
  __syncthreads();

  int lane = t&63, wv = t>>6, wr = wv>>1, wc = wv&1;
  int mq = lane&15, quad = lane>>4;
  const f16* hpb = hpB + (long)bh*128*128*8;
  f32x4 acc[4][4];
  #pragma unroll
  for(int a=0;a<4;a++)
    #pragma unroll
    for(int c=0;c<4;c++) acc[a][c] = (f32x4){0.f,0.f,0.f,0.f};

  int prow = t>>1, pjg = t&1;
  float srow = ssr[prow], mrow = mlr[prow];
  float zacc = 0.f;

  for(int jt=0; jt<32; jt++){
    // issue B-fragment global loads early (independent of P)
    f16x8 bf[4];
    #pragma unroll
    for(int nt=0;nt<4;nt++){
      int c  = wc*64 + nt*16 + mq;
      int jc = jt*4 + quad;
      bf[nt] = *(const f16x8*)(hpb + (jc*128 + c)*8);
    }
    // P tile: 2 threads per row, 16 j each
    {
      unsigned word = (ams[prow*33 + jt] >> (pjg*16)) & 0xffffu;
      const float4* dp4 = (const float4*)(dd + jt*32 + pjg*16);
      float4 dA = dp4[0], dB = dp4[1], dC = dp4[2], dD = dp4[3];
      float dv[16] = {dA.x,dA.y,dA.z,dA.w, dB.x,dB.y,dB.z,dB.w,
                      dC.x,dC.y,dC.z,dC.w, dD.x,dD.y,dD.z,dD.w};
      f16x8 plo, phi;
      #pragma unroll
      for(int jj=0;jj<16;jj++){
        float x  = srow + dv[jj];
        float sc = fmaxf(x, 0.2f*x);
        float e  = __expf(sc - mrow);
        float p  = ((word >> jj) & 1u) ? e : 0.0f;
        zacc += p;
        if (jj < 8) plo[jj] = (f16)p; else phi[jj-8] = (f16)p;
      }
      *(f16x8*)(Pl + prow*40 + pjg*16)     = plo;
      *(f16x8*)(Pl + prow*40 + pjg*16 + 8) = phi;
    }
    __syncthreads();
    f16x8 af[4];
    #pragma unroll
    for(int mt=0;mt<4;mt++)
      af[mt] = *(const f16x8*)(Pl + (wr*64 + mt*16 + mq)*40 + quad*8);
    #pragma unroll
    for(int mt=0;mt<4;mt++)
      #pragma unroll
      for(int nt=0;nt<4;nt++)
        acc[mt][nt] = __builtin_amdgcn_mfma_f32_16x16x32_f16(af[mt], bf[nt], acc[mt][nt], 0,0,0);
    __syncthreads();
  }
  // Z per row (2 threads), then scale+store
  zacc += __shfl_xor(zacc, 1);
  if ((t&1)==0) zin[prow] = 1.0f / zacc;
  __syncthreads();
  float* pout = part + (long)bh*1024*128 + (long)i0*128;
  #pragma unroll
  for(int mt=0;mt<4;mt++){
    float zf[4];
    #pragma unroll
    for(int rg=0;rg<4;rg++) zf[rg] = 0.125f * zin[wr*64 + mt*16 + quad*4 + rg];
    #pragma unroll
    for(int nt=0;nt<4;nt++){
      int c = wc*64 + nt*16 + mq;
      #pragma unroll
      for(int rg=0;rg<4;rg++){
        int il = wr*64 + mt*16 + quad*4 + rg;
        pout[il*128 + c] = acc[mt][nt][rg] * zf[rg];
      }
    }
  }
}

// ---------------- finalize: mean heads + bias (+relu), emit f32 and f16 ----------------
__global__ void k_fin(const float* __restrict__ part, const float* __restrict__ bias,
                      float* __restrict__ x32, f16* __restrict__ x16, int do_relu){
  int idx = blockIdx.x*256 + threadIdx.x;     // b*131072 + n*128 + c
  int c = idx & 127;
  int b = idx >> 17;
  int nc = idx & 131071;
  const float* p = part + (long)b*8*131072 + nc;
  float s = 0.f;
  #pragma unroll
  for(int h=0;h<8;h++) s += p[h*131072];
  float v = s + bias[c];                      // part already carries the 1/8
  if (do_relu) v = fmaxf(v, 0.0f);
  x32[idx] = v;
  if (x16) x16[idx] = (f16)v;
}

// ---------------- max-pool over nodes + predictor ----------------
__global__ void k_pool1(const float* __restrict__ x1, const float* __restrict__ x2,
                        const float* __restrict__ x3, float* __restrict__ pP){
  int bid = blockIdx.x;            // b*8 + ch
  int ch = bid & 7, b = bid >> 3;
  int t = threadIdx.x;
  for(int f = t; f < 384; f += 256){
    const float* buf = (f < 128) ? x1 : ((f < 256) ? x2 : x3);
    int c = f & 127;
    const float* p = buf + ((long)b*1024 + ch*128)*128 + c;
    float mx = -3.4e38f;
    for(int n=0;n<128;n++) mx = fmaxf(mx, p[n*128]);
    pP[bid*384 + f] = mx;
  }
}

__global__ void k_pool2(const float* __restrict__ pP, const float* __restrict__ pw,
                        const float* __restrict__ pb, float* __restrict__ out){
  __shared__ float pl[384];
  int b = blockIdx.x, t = threadIdx.x;
  for(int f = t; f < 384; f += 256){
    float mx = -3.4e38f;
    #pragma unroll
    for(int ch=0;ch<8;ch++) mx = fmaxf(mx, pP[(b*8+ch)*384 + f]);
    pl[f] = mx;
  }
  __syncthreads();
  if (t < 64){
    float a0 = 0.f, a1 = 0.f;
    #pragma unroll
    for(int k=0;k<6;k++){
      int f = t + 64*k;
      float v = pl[f];
      a0 = fmaf(v, pw[f*2],   a0);
      a1 = fmaf(v, pw[f*2+1], a1);
    }
    #pragma unroll
    for(int o=1;o<64;o<<=1){ a0 += __shfl_xor(a0,o); a1 += __shfl_xor(a1,o); }
    if (t == 0){ out[b*2] = a0 + pb[0]; out[b*2+1] = a1 + pb[1]; }
  }
}

// ---------------- launcher ----------------
extern "C" void kernel_launch(void* const* d_in, const int* in_sizes, int n_in,
                              void* d_out, int out_size, void* d_ws, size_t ws_size,
                              hipStream_t stream) {
  const float* x   = (const float*)d_in[0];
  const float* adj = (const float*)d_in[1];
  const float* w1  = (const float*)d_in[2];
  const float* as1 = (const float*)d_in[3];
  const float* ad1 = (const float*)d_in[4];
  const float* b1  = (const float*)d_in[5];
  const float* w2  = (const float*)d_in[6];
  const float* as2 = (const float*)d_in[7];
  const float* ad2 = (const float*)d_in[8];
  const float* b2  = (const float*)d_in[9];
  const float* w3  = (const float*)d_in[10];
  const float* as3 = (const float*)d_in[11];
  const float* ad3 = (const float*)d_in[12];
  const float* b3  = (const float*)d_in[13];
  const float* pw  = (const float*)d_in[14];
  const float* pb  = (const float*)d_in[15];

  char* ws = (char*)d_ws;
  f16*      x16a = (f16*)ws;                 ws += (size_t)1048576*2;
  f16*      x16b = (f16*)ws;                 ws += (size_t)1048576*2;
  f16*      wB   = (f16*)ws;                 ws += (size_t)393216*2;
  unsigned* am   = (unsigned*)ws;            ws += (size_t)8*1024*32*4;
  f16*      hpB  = (f16*)ws;                 ws += (size_t)8*8*1024*128*2;
  float*    sarr = (float*)ws;               ws += (size_t)65536*4;
  float*    darr = (float*)ws;               ws += (size_t)65536*4;
  float*    part = (float*)ws;               ws += (size_t)8*8*1024*128*4;
  float*    x32_1= (float*)ws;               ws += (size_t)1048576*4;
  float*    x32_2= (float*)ws;               ws += (size_t)1048576*4;
  float*    x32_3= (float*)ws;               ws += (size_t)1048576*4;
  float*    pP   = (float*)ws;               ws += (size_t)8*8*384*4;

  k_conv_x<<<512, 256, 0, stream>>>(x, x16a);
  k_conv_w<<<192, 256, 0, stream>>>(w1, w2, w3, wB);
  k_adjm<<<2048, 256, 0, stream>>>(adj, am);

  // layer 1
  k_hp  <<<512, 256, 0, stream>>>(x16a, wB,            as1, ad1, hpB, sarr, darr);
  k_attn<<<512, 256, 0, stream>>>(hpB, sarr, darr, am, part);
  k_fin <<<4096,256, 0, stream>>>(part, b1, x32_1, x16b, 1);
  // layer 2
  k_hp  <<<512, 256, 0, stream>>>(x16b, wB + 131072,   as2, ad2, hpB, sarr, darr);
  k_attn<<<512, 256, 0, stream>>>(hpB, sarr, darr, am, part);
  k_fin <<<4096,256, 0, stream>>>(part, b2, x32_2, x16a, 1);
  // layer 3
  k_hp  <<<512, 256, 0, stream>>>(x16a, wB + 262144,   as3, ad3, hpB, sarr, darr);
  k_attn<<<512, 256, 0, stream>>>(hpB, sarr, darr, am, part);
  k_fin <<<4096,256, 0, stream>>>(part, b3, x32_3, nullptr, 0);

  k_pool1<<<64, 256, 0, stream>>>(x32_1, x32_2, x32_3, pP);
  k_pool2<<<8,  256, 0, stream>>>(pP, pw, pb, (float*)d_out);
}

// Round 3
// 292.850 us; speedup vs baseline: 1.1344x; 1.1344x over previous
//
#include <hip/hip_runtime.h>
#include <hip/hip_fp16.h>

#define BB 8
#define NN 1024
#define FF 128
#define HH 8

typedef _Float16 f16;
typedef f16  f16x8 __attribute__((ext_vector_type(8)));
typedef f16  f16x4 __attribute__((ext_vector_type(4)));
typedef float f32x4 __attribute__((ext_vector_type(4)));

#define L2E 1.44269504f

__device__ __forceinline__ float lrelu(float x){ return fmaxf(x, 0.2f*x); }

// ---------------- preprocessing kernels ----------------

__global__ void k_conv_x(const float* __restrict__ x, f16* __restrict__ o){
  int i = (blockIdx.x*256 + threadIdx.x)*8;
  float4 a = *(const float4*)(x+i), b = *(const float4*)(x+i+4);
  f16x8 v;
  v[0]=(f16)a.x; v[1]=(f16)a.y; v[2]=(f16)a.z; v[3]=(f16)a.w;
  v[4]=(f16)b.x; v[5]=(f16)b.y; v[6]=(f16)b.z; v[7]=(f16)b.w;
  *(f16x8*)(o+i) = v;
}

// wB layout: [l][h][fc=f/8][c][8]  (B-fragment friendly)
__global__ void k_conv_w(const float* __restrict__ w1, const float* __restrict__ w2,
                         const float* __restrict__ w3, f16* __restrict__ wB){
  int e = blockIdx.x*256 + threadIdx.x;        // 49152 total
  int fc = e & 15, c = (e>>4)&127, h = (e>>11)&7, l = e>>14;
  const float* w = (l==0) ? w1 : ((l==1) ? w2 : w3);
  f16x8 v;
  #pragma unroll
  for(int j=0;j<8;j++) v[j] = (f16)w[(h*128 + fc*8 + j)*128 + c];
  *(f16x8*)(wB + (((l*8+h)*16 + fc)*128 + c)*8) = v;
}

// adjacency bitmask: am[b*1024+n][32 words]
__global__ void k_adjm(const float* __restrict__ adj, unsigned* __restrict__ am){
  int wv = threadIdx.x >> 6, lane = threadIdx.x & 63;
  int r = blockIdx.x*4 + wv;                  // 0..8191
  const float* row = adj + (long)r*1024;
  for(int g=0; g<16; g++){
    float v = row[g*64 + lane];
    unsigned long long mb = __ballot(v > 0.0f);
    if (lane == 0){
      am[r*32 + 2*g]   = (unsigned)mb;
      am[r*32 + 2*g+1] = (unsigned)(mb >> 32);
    }
  }
}

// ---------------- hp GEMM: hp = x @ w  (+tanh -> s,d) ----------------
// grid: b*64 + h*8 + it   (512 blocks, 256 threads)
// hpB layout: [b][h][jc=node/8][c][8]
__global__ __launch_bounds__(256,2) void k_hp(
    const f16* __restrict__ xin,      // [B][N][128] f16
    const f16* __restrict__ wBl,      // [H][16][128][8]
    const float* __restrict__ asrc, const float* __restrict__ adst,  // [H][128]
    f16* __restrict__ hpB,            // [B][H][128][128][8]
    float* __restrict__ sarr, float* __restrict__ darr)              // [B][H][1024]
{
  __shared__ f16 xs[128*136];     // x tile, later reused as tanh tile
  __shared__ float asl[128], adl[128];
  int t = threadIdx.x;
  int bid = blockIdx.x;
  int it = bid & 7, h = (bid>>3)&7, b = bid>>6;
  int i0 = it*128;
  {
    const f16* src = xin + (long)(b*1024 + i0)*128;
    int fc = t & 15, r0 = t >> 4;
    #pragma unroll
    for(int p=0;p<8;p++){
      int r = r0 + p*16;
      f16x8 v = *(const f16x8*)(src + r*128 + fc*8);
      *(f16x8*)(xs + r*136 + fc*8) = v;
    }
  }
  if (t < 128){ asl[t] = asrc[h*128+t]; adl[t] = adst[h*128+t]; }
  __syncthreads();

  int lane = t & 63, wv = t>>6, wr = wv>>1, wc = wv&1;
  int mq = lane & 15, quad = lane >> 4;
  f32x4 acc[4][4];
  #pragma unroll
  for(int a=0;a<4;a++)
    #pragma unroll
    for(int c=0;c<4;c++) acc[a][c] = (f32x4){0.f,0.f,0.f,0.f};

  const f16* wh = wBl + h*16*128*8;
  #pragma unroll
  for(int ks=0; ks<4; ks++){
    f16x8 af[4], bf[4];
    #pragma unroll
    for(int mt=0; mt<4; mt++)
      af[mt] = *(const f16x8*)(xs + (wr*64 + mt*16 + mq)*136 + ks*32 + quad*8);
    #pragma unroll
    for(int nt=0; nt<4; nt++){
      int c  = wc*64 + nt*16 + mq;
      int fc = ks*4 + quad;
      bf[nt] = *(const f16x8*)(wh + (fc*128 + c)*8);
    }
    #pragma unroll
    for(int mt=0; mt<4; mt++)
      #pragma unroll
      for(int nt=0; nt<4; nt++)
        acc[mt][nt] = __builtin_amdgcn_mfma_f32_16x16x32_f16(af[mt], bf[nt], acc[mt][nt], 0,0,0);
  }
  __syncthreads();          // xs dead -> reuse as tanh tile
  f16* tt = xs;             // [128][136]
  f16* hpb = hpB + (long)(b*8+h)*128*128*8;
  #pragma unroll
  for(int mt=0; mt<4; mt++){
    #pragma unroll
    for(int nt=0; nt<4; nt++){
      int c = wc*64 + nt*16 + mq;
      f16x4 pk;
      #pragma unroll
      for(int rg=0; rg<4; rg++){
        float v = acc[mt][nt][rg];
        pk[rg] = (f16)v;
        int il = wr*64 + mt*16 + quad*4 + rg;    // 0..127
        float e2 = __expf(2.0f*v);
        float th = 1.0f - 2.0f*__builtin_amdgcn_rcpf(e2 + 1.0f);
        tt[il*136 + c] = (f16)th;
      }
      int il0 = wr*64 + mt*16 + quad*4;
      int inode = i0 + il0;
      *(f16x4*)(hpb + ((long)(inode>>3)*128 + c)*8 + (inode&7)) = pk;  // 8B packed store
    }
  }
  __syncthreads();
  {
    int r = t>>1, hf = t&1;
    float s_p = 0.f, d_p = 0.f;
    #pragma unroll
    for(int q=0;q<8;q++){
      f16x8 tv = *(const f16x8*)(tt + r*136 + hf*64 + q*8);
      #pragma unroll
      for(int j=0;j<8;j++){
        float tvf = (float)tv[j];
        int c = hf*64 + q*8 + j;
        s_p = fmaf(tvf, asl[c], s_p);
        d_p = fmaf(tvf, adl[c], d_p);
      }
    }
    s_p += __shfl_xor(s_p, 1);
    d_p += __shfl_xor(d_p, 1);
    if (hf == 0){
      sarr[(b*8+h)*1024 + i0 + r] = s_p;
      darr[(b*8+h)*1024 + i0 + r] = d_p;
    }
  }
}

// ---------------- attention (j-split, sparse P, double-buffered) ----------------
// grid: 1024 blocks: bid = q*64 + bh, q = it*2 + jh  (same-bh blocks -> same XCD)
// Unnormalized partial sums -> part (f16), partial z -> zpart (f32)
__global__ __launch_bounds__(256,4) void k_attn(
    const f16* __restrict__ hpB,      // [B*H][128][128][8]
    const float* __restrict__ sarr, const float* __restrict__ darr,
    const unsigned* __restrict__ am,  // [B*1024][32]
    f16* __restrict__ part,           // [2*64][1024][128] f16, unnormalized
    float* __restrict__ zpart)        // [2*64][1024]
{
  __shared__ float ddl[512];          // log2e-scaled d for this j-half
  __shared__ float wred[4];
  __shared__ f16 Pl[2][128*40];
  int t = threadIdx.x;
  int bid = blockIdx.x;
  int bh = bid & 63, q = bid >> 6;
  int jh = q & 1, it = q >> 1;
  int i0 = it*128, j0 = jh*512;
  int b = bh >> 3;

  // d: global max over ALL 1024 (shared m bound across j-halves), stage scaled half
  {
    float4 v = *(const float4*)(darr + bh*1024 + t*4);
    float mx = fmaxf(fmaxf(v.x,v.y), fmaxf(v.z,v.w));
    #pragma unroll
    for(int o=1;o<64;o<<=1) mx = fmaxf(mx, __shfl_xor(mx, o));
    if ((t&63)==0) wred[t>>6] = mx;
    int base = t*4 - j0;
    if (base >= 0 && base < 512){
      float4 s = make_float4(v.x*L2E, v.y*L2E, v.z*L2E, v.w*L2E);
      *(float4*)(ddl + base) = s;
    }
  }
  __syncthreads();
  float Dml = fmaxf(fmaxf(wred[0],wred[1]), fmaxf(wred[2],wred[3])) * L2E;

  int prow = t>>1, pjg = t&1;
  float srowl = sarr[bh*1024 + i0 + prow] * L2E;
  float ml = srowl + Dml;
  float mrowl = fmaxf(ml, 0.2f*ml);   // log2-domain upper bound of masked scores
  const unsigned* amrow = am + ((long)(b*1024 + i0 + prow))*32 + jh*16;

  int lane = t&63, wv = t>>6, wr = wv>>1, wc = wv&1;
  int mq = lane&15, quad = lane>>4;
  const f16* hpb = hpB + (long)bh*128*128*8;
  f32x4 acc[4][4];
  #pragma unroll
  for(int a=0;a<4;a++)
    #pragma unroll
    for(int c=0;c<4;c++) acc[a][c] = (f32x4){0.f,0.f,0.f,0.f};
  float zacc = 0.f;
  f16x8 zerov = (f16x8){0,0,0,0,0,0,0,0};

  unsigned wcur = amrow[0];
  for(int jt=0; jt<16; jt++){
    // B fragments from global (L2-resident via XCD swizzle)
    f16x8 bf[4];
    #pragma unroll
    for(int nt=0;nt<4;nt++){
      int c  = wc*64 + nt*16 + mq;
      int jc = jh*64 + jt*4 + quad;
      bf[nt] = *(const f16x8*)(hpb + (jc*128 + c)*8);
    }
    unsigned wnx = (jt < 15) ? amrow[jt+1] : 0u;
    // sparse P tile: zero-fill own region, scatter exp at set bits
    f16* Pb = Pl[jt&1];
    f16* myp = Pb + prow*40 + pjg*16;
    *(f16x8*)(myp)     = zerov;
    *(f16x8*)(myp + 8) = zerov;
    unsigned word = (wcur >> (pjg*16)) & 0xffffu;
    const float* dloc = ddl + jt*32 + pjg*16;
    while(word){
      int j = __builtin_ctz(word);
      word &= word - 1u;
      float xl  = srowl + dloc[j];
      float scl = fmaxf(xl, 0.2f*xl);
      float e   = __builtin_amdgcn_exp2f(scl - mrowl);
      zacc += e;
      myp[j] = (f16)e;
    }
    __syncthreads();
    #pragma unroll
    for(int mt=0;mt<4;mt++){
      f16x8 a = *(const f16x8*)(Pb + (wr*64 + mt*16 + mq)*40 + quad*8);
      #pragma unroll
      for(int nt=0;nt<4;nt++)
        acc[mt][nt] = __builtin_amdgcn_mfma_f32_16x16x32_f16(a, bf[nt], acc[mt][nt], 0,0,0);
    }
    wcur = wnx;
  }
  // partial z per row
  zacc += __shfl_xor(zacc, 1);
  if (pjg == 0) zpart[(jh*64 + bh)*1024 + i0 + prow] = zacc;
  // store unnormalized partial sums (f16)
  f16* pout = part + ((long)(jh*64 + bh)*1024 + i0)*128;
  #pragma unroll
  for(int mt=0;mt<4;mt++){
    #pragma unroll
    for(int nt=0;nt<4;nt++){
      int c = wc*64 + nt*16 + mq;
      #pragma unroll
      for(int rg=0;rg<4;rg++){
        int il = wr*64 + mt*16 + quad*4 + rg;
        pout[il*128 + c] = (f16)acc[mt][nt][rg];
      }
    }
  }
}

// ---------------- zinv = 0.125/(z0+z1) ----------------
__global__ void k_zinv(const float* __restrict__ zp, float* __restrict__ zinv){
  int i = blockIdx.x*256 + threadIdx.x;   // 65536
  zinv[i] = 0.125f / (zp[i] + zp[65536 + i]);
}

// ---------------- finalize: combine halves, mean heads, bias(+relu) ----------------
__global__ void k_fin(const f16* __restrict__ part, const float* __restrict__ zinv,
                      const float* __restrict__ bias,
                      float* __restrict__ x32, f16* __restrict__ x16, int do_relu){
  int idx = blockIdx.x*256 + threadIdx.x;   // 131072: b(3)|n(10)|c8(4)
  int c8 = idx & 15, n = (idx>>4)&1023, b = idx>>14;
  float s[8];
  #pragma unroll
  for(int j=0;j<8;j++) s[j] = 0.f;
  #pragma unroll
  for(int h=0;h<8;h++){
    int bh = b*8 + h;
    float zi = zinv[bh*1024 + n];
    f16x8 p0 = *(const f16x8*)(part + ((long)bh*1024 + n)*128 + c8*8);
    f16x8 p1 = *(const f16x8*)(part + ((long)(64+bh)*1024 + n)*128 + c8*8);
    #pragma unroll
    for(int j=0;j<8;j++) s[j] = fmaf((float)p0[j] + (float)p1[j], zi, s[j]);
  }
  int o = (b*1024 + n)*128 + c8*8;
  f16x8 h8;
  float ov[8];
  #pragma unroll
  for(int j=0;j<8;j++){
    float v = s[j] + bias[c8*8 + j];
    if (do_relu) v = fmaxf(v, 0.f);
    ov[j] = v;
    h8[j] = (f16)v;
  }
  *(float4*)(x32 + o)     = make_float4(ov[0],ov[1],ov[2],ov[3]);
  *(float4*)(x32 + o + 4) = make_float4(ov[4],ov[5],ov[6],ov[7]);
  if (x16) *(f16x8*)(x16 + o) = h8;
}

// ---------------- max-pool over nodes + predictor ----------------
__global__ void k_pool1(const float* __restrict__ x1, const float* __restrict__ x2,
                        const float* __restrict__ x3, float* __restrict__ pP){
  int bid = blockIdx.x;            // b*8 + ch
  int ch = bid & 7, b = bid >> 3;
  int t = threadIdx.x;
  for(int f = t; f < 384; f += 256){
    const float* buf = (f < 128) ? x1 : ((f < 256) ? x2 : x3);
    int c = f & 127;
    const float* p = buf + ((long)b*1024 + ch*128)*128 + c;
    float mx = -3.4e38f;
    for(int n=0;n<128;n++) mx = fmaxf(mx, p[n*128]);
    pP[bid*384 + f] = mx;
  }
}

__global__ void k_pool2(const float* __restrict__ pP, const float* __restrict__ pw,
                        const float* __restrict__ pb, float* __restrict__ out){
  __shared__ float pl[384];
  int b = blockIdx.x, t = threadIdx.x;
  for(int f = t; f < 384; f += 256){
    float mx = -3.4e38f;
    #pragma unroll
    for(int ch=0;ch<8;ch++) mx = fmaxf(mx, pP[(b*8+ch)*384 + f]);
    pl[f] = mx;
  }
  __syncthreads();
  if (t < 64){
    float a0 = 0.f, a1 = 0.f;
    #pragma unroll
    for(int k=0;k<6;k++){
      int f = t + 64*k;
      float v = pl[f];
      a0 = fmaf(v, pw[f*2],   a0);
      a1 = fmaf(v, pw[f*2+1], a1);
    }
    #pragma unroll
    for(int o=1;o<64;o<<=1){ a0 += __shfl_xor(a0,o); a1 += __shfl_xor(a1,o); }
    if (t == 0){ out[b*2] = a0 + pb[0]; out[b*2+1] = a1 + pb[1]; }
  }
}

// ---------------- launcher ----------------
extern "C" void kernel_launch(void* const* d_in, const int* in_sizes, int n_in,
                              void* d_out, int out_size, void* d_ws, size_t ws_size,
                              hipStream_t stream) {
  const float* x   = (const float*)d_in[0];
  const float* adj = (const float*)d_in[1];
  const float* w1  = (const float*)d_in[2];
  const float* as1 = (const float*)d_in[3];
  const float* ad1 = (const float*)d_in[4];
  const float* b1  = (const float*)d_in[5];
  const float* w2  = (const float*)d_in[6];
  const float* as2 = (const float*)d_in[7];
  const float* ad2 = (const float*)d_in[8];
  const float* b2  = (const float*)d_in[9];
  const float* w3  = (const float*)d_in[10];
  const float* as3 = (const float*)d_in[11];
  const float* ad3 = (const float*)d_in[12];
  const float* b3  = (const float*)d_in[13];
  const float* pw  = (const float*)d_in[14];
  const float* pb  = (const float*)d_in[15];

  char* ws = (char*)d_ws;
  f16*      x16a = (f16*)ws;                 ws += (size_t)1048576*2;
  f16*      x16b = (f16*)ws;                 ws += (size_t)1048576*2;
  f16*      wB   = (f16*)ws;                 ws += (size_t)393216*2;
  unsigned* am   = (unsigned*)ws;            ws += (size_t)8*1024*32*4;
  f16*      hpB  = (f16*)ws;                 ws += (size_t)8*8*1024*128*2;
  float*    sarr = (float*)ws;               ws += (size_t)65536*4;
  float*    darr = (float*)ws;               ws += (size_t)65536*4;
  f16*      part = (f16*)ws;                 ws += (size_t)2*64*1024*128*2;
  float*    zp   = (float*)ws;               ws += (size_t)2*65536*4;
  float*    zinv = (float*)ws;               ws += (size_t)65536*4;
  float*    x32_1= (float*)ws;               ws += (size_t)1048576*4;
  float*    x32_2= (float*)ws;               ws += (size_t)1048576*4;
  float*    x32_3= (float*)ws;               ws += (size_t)1048576*4;
  float*    pP   = (float*)ws;               ws += (size_t)8*8*384*4;

  k_conv_x<<<512, 256, 0, stream>>>(x, x16a);
  k_conv_w<<<192, 256, 0, stream>>>(w1, w2, w3, wB);
  k_adjm<<<2048, 256, 0, stream>>>(adj, am);

  // layer 1
  k_hp  <<<512, 256, 0, stream>>>(x16a, wB,            as1, ad1, hpB, sarr, darr);
  k_attn<<<1024,256, 0, stream>>>(hpB, sarr, darr, am, part, zp);
  k_zinv<<<256, 256, 0, stream>>>(zp, zinv);
  k_fin <<<512, 256, 0, stream>>>(part, zinv, b1, x32_1, x16b, 1);
  // layer 2
  k_hp  <<<512, 256, 0, stream>>>(x16b, wB + 131072,   as2, ad2, hpB, sarr, darr);
  k_attn<<<1024,256, 0, stream>>>(hpB, sarr, darr, am, part, zp);
  k_zinv<<<256, 256, 0, stream>>>(zp, zinv);
  k_fin <<<512, 256, 0, stream>>>(part, zinv, b2, x32_2, x16a, 1);
  // layer 3
  k_hp  <<<512, 256, 0, stream>>>(x16a, wB + 262144,   as3, ad3, hpB, sarr, darr);
  k_attn<<<1024,256, 0, stream>>>(hpB, sarr, darr, am, part, zp);
  k_zinv<<<256, 256, 0, stream>>>(zp, zinv);
  k_fin <<<512, 256, 0, stream>>>(part, zinv, b3, x32_3, nullptr, 0);

  k_pool1<<<64, 256, 0, stream>>>(x32_1, x32_2, x32_3, pP);
  k_pool2<<<8,  256, 0, stream>>>(pP, pw, pb, (float*)d_out);
}